// Round 8
// baseline (979.668 us; speedup 1.0000x reference)
//
#include <hip/hip_runtime.h>

#define BATCHN 131072
#define FD 512
#define F2 256
#define NOBJ 100000
#define NPRED 2000
#define LDSTR 520   // bf16 tile row stride (proven conflict-free with this ds_read pattern)
#define RPB 128     // rows per scan/bnrelu block

typedef __bf16 bf16x8 __attribute__((ext_vector_type(8)));
typedef float f32x4 __attribute__((ext_vector_type(4)));

__device__ __forceinline__ ushort f2bf(float f) {
  union { float f; uint u; } c; c.f = f;
  uint u = c.u;
  u += 0x7FFFu + ((u >> 16) & 1u);   // RNE
  return (ushort)(u >> 16);
}

__device__ __forceinline__ void gload16(const void* g, void* l) {
  __builtin_amdgcn_global_load_lds(
      (const __attribute__((address_space(1))) void*)g,
      (__attribute__((address_space(3))) void*)l, 16, 0, 0);
}

// ---------------- ws layout (float units) ----------------
// cnt (int): subj[100000], obj[100000], predi[2000] at 0 / 100000 / 200000
#define WS_STATS123 202752   // 3*1024: per-e [sum512, sumsq512]
#define WS_S4       205824   // 64 slots * [sum256, sumsq256]
#define WS_SCSH123  238592   // 3*1024
#define WS_SCSH4    241664   // 512
#define WS_W4BF     242176   // ushort[256*512] = 65536 floats
#define WS_WBF1     307712   // bf16[100000*512] = 25.6M floats (post-BN-relu)
#define WS_WBF2     25907712 // bf16[100000*512]
#define WS_WBF3     51507712 // bf16[2000*512] = 512000 floats
#define WS_A1       52019712 // bf16[100000*256] = 12.8M floats
#define WS_A2       64819712 // bf16[100000*256]
#define WS_A3       77619712 // bf16[2000*256] = 256000 floats
// end: 77,875,712 floats = 311.5 MB (ws ~800 MB per harness fill)
#define WS_H        WS_WBF1  // bf16[131072*256] overlays WBF1 (dead by then)

// ---------------- histogram of indices ----------------
__global__ __launch_bounds__(256) void k_hist(
    const int* __restrict__ subj, const int* __restrict__ obj,
    const int* __restrict__ predi, int* __restrict__ cnt)
{
  int b = blockIdx.x * 256 + threadIdx.x;
  atomicAdd(&cnt[subj[b]], 1);
  atomicAdd(&cnt[NOBJ + obj[b]], 1);
  atomicAdd(&cnt[2 * NOBJ + predi[b]], 1);
}

// ---------------- BN stats: weighted scan over W (stats only) ----------------
__global__ __launch_bounds__(256) void k_scan(
    const float* __restrict__ W, const int* __restrict__ cn,
    float* __restrict__ statsE, int N)
{
  __shared__ float redS[512], redQ[512];
  int t = threadIdx.x;
  redS[t] = 0.f; redS[t + 256] = 0.f; redQ[t] = 0.f; redQ[t + 256] = 0.f;
  __syncthreads();
  int c = t & 63, rg = t >> 6;   // lane c -> feats [8c,8c+8); wave covers full 2KB row
  int base = blockIdx.x * RPB;
  int end = min(N, base + RPB);
  float s[8], q[8];
  #pragma unroll
  for (int j = 0; j < 8; ++j) { s[j] = 0.f; q[j] = 0.f; }

  #pragma unroll 4
  for (int r = base + rg; r < end; r += 4) {
    const float* row = W + (size_t)r * FD + c * 8;
    float4 va = *(const float4*)(row);
    float4 vb = *(const float4*)(row + 4);
    float wv = (float)cn[r];
    float x[8] = {va.x, va.y, va.z, va.w, vb.x, vb.y, vb.z, vb.w};
    #pragma unroll
    for (int j = 0; j < 8; ++j) {
      float wx = wv * x[j];
      s[j] += wx; q[j] = fmaf(wx, x[j], q[j]);
    }
  }

  #pragma unroll
  for (int j = 0; j < 8; ++j) {
    atomicAdd(&redS[c * 8 + j], s[j]);
    atomicAdd(&redQ[c * 8 + j], q[j]);
  }
  __syncthreads();
  atomicAdd(&statsE[t],        redS[t]);
  atomicAdd(&statsE[t + 256],  redS[t + 256]);
  atomicAdd(&statsE[512 + t],  redQ[t]);
  atomicAdd(&statsE[768 + t],  redQ[t + 256]);
}

__global__ void k_fin123(const float* __restrict__ stats,
                         const float* __restrict__ g1, const float* __restrict__ be1,
                         const float* __restrict__ g2, const float* __restrict__ be2,
                         const float* __restrict__ g3, const float* __restrict__ be3,
                         float* __restrict__ scsh)
{
  int e = blockIdx.x, f = threadIdx.x;  // 3 x 512
  const float* g  = (e == 0) ? g1  : (e == 1 ? g2  : g3);
  const float* be = (e == 0) ? be1 : (e == 1 ? be2 : be3);
  float S = stats[e * 1024 + f], SS = stats[e * 1024 + 512 + f];
  const float invB = 1.f / (float)BATCHN;
  float mean = S * invB;
  float var  = SS * invB - mean * mean;
  if (!(var >= 0.f && var < 1e30f)) var = 1.f;
  if (!(mean > -1e30f && mean < 1e30f)) mean = 0.f;
  float r = rsqrtf(var + 1e-5f);
  float sc = g[f] * r;
  scsh[e * 1024 + f]       = sc;
  scsh[e * 1024 + 512 + f] = be[f] - mean * sc;
}

// ---------------- W fp32 -> relu(bn(W)) bf16 (streaming; used rows only) ----------------
__global__ __launch_bounds__(256) void k_bnrelu(
    const float* __restrict__ W, const int* __restrict__ cn,
    const float* __restrict__ scshE, ushort* __restrict__ wbf, int N)
{
  int t = threadIdx.x;
  int c = t & 63, rg = t >> 6;
  float sc[8], sh[8];
  #pragma unroll
  for (int j = 0; j < 8; ++j) {
    sc[j] = scshE[c * 8 + j];
    sh[j] = scshE[512 + c * 8 + j];
  }
  int base = blockIdx.x * RPB;
  int end = min(N, base + RPB);
  #pragma unroll 4
  for (int r = base + rg; r < end; r += 4) {
    if (cn[r] == 0) continue;    // wave-uniform skip
    const float* row = W + (size_t)r * FD + c * 8;
    float4 va = *(const float4*)(row);
    float4 vb = *(const float4*)(row + 4);
    float x[8] = {va.x, va.y, va.z, va.w, vb.x, vb.y, vb.z, vb.w};
    union { ushort o[8]; uint4 v; } u;
    #pragma unroll
    for (int j = 0; j < 8; ++j) {
      float v = fmaxf(fmaf(sc[j], x[j], sh[j]), 0.f);
      v = fminf(v, 60000.f);
      u.o[j] = f2bf(v);
    }
    *(uint4*)&wbf[(size_t)r * FD + c * 8] = u.v;
  }
}

// ---------------- W4 fp32 -> bf16 ----------------
__global__ __launch_bounds__(256) void k_convW4(const float* __restrict__ W4,
                                                ushort* __restrict__ w4bf)
{
  int i = (blockIdx.x * 256 + threadIdx.x) * 4;
  float4 v = *(const float4*)(W4 + i);
  ushort4 o = {f2bf(v.x), f2bf(v.y), f2bf(v.z), f2bf(v.w)};
  *(ushort4*)(w4bf + i) = o;
}

// ---------------- pure GEMM: A = wbf(32-row tile) @ W4^T ----------------
// A staged via global_load_lds (async, register-free): one instr per 1KB row,
// wave-uniform LDS base r*LDSTR keeps the proven padded layout. No VALU staging.
__global__ __launch_bounds__(256) void k_gemmA(
    const ushort* __restrict__ wbf, const ushort* __restrict__ w4bf,
    const int* __restrict__ cn, ushort* __restrict__ A, int N)
{
  alignas(16) __shared__ ushort tileL[32 * LDSTR];  // reused as bf16 bounce [32][268]
  __shared__ int cnOk[32];
  int t = threadIdx.x;
  int rowBase = blockIdx.x * 32;
  int w = t >> 6, lane = t & 63, m = lane & 15, q = lane >> 4;

  if (t < 32) { int gr = rowBase + t; cnOk[t] = (gr < N) && (cn[gr] != 0); }

  // async stage: wave w fills rows {w, w+4, ..., w+28}
  #pragma unroll
  for (int u = 0; u < 8; ++u) {
    int r = w + 4 * u;
    int gr = rowBase + r; if (gr >= N) gr = N - 1;   // dup/garbage rows never written out
    gload16(wbf + (size_t)gr * FD + lane * 8, &tileL[r * LDSTR]);
  }

  const ushort* w4p = w4bf + ((size_t)(64 * w + m)) * FD + q * 8;
  bf16x8 bc0 = *(const bf16x8*)(w4p + 0 * 16 * FD);
  bf16x8 bc1 = *(const bf16x8*)(w4p + 1 * 16 * FD);
  bf16x8 bc2 = *(const bf16x8*)(w4p + 2 * 16 * FD);
  bf16x8 bc3 = *(const bf16x8*)(w4p + 3 * 16 * FD);
  __syncthreads();   // drains vmcnt: gload_lds data landed in LDS

  // MFMA: 32x256x512, B software-pipelined 1-deep
  f32x4 acc[2][4];
  #pragma unroll
  for (int mi = 0; mi < 2; ++mi)
    #pragma unroll
    for (int ni = 0; ni < 4; ++ni)
      acc[mi][ni] = (f32x4){0.f, 0.f, 0.f, 0.f};
  const ushort* fpL = tileL + m * LDSTR + q * 8;

  for (int kk = 0; kk < 16; ++kk) {
    int kc = kk * 32;
    bf16x8 af0 = *(const bf16x8*)(fpL + kc);
    bf16x8 af1 = *(const bf16x8*)(fpL + 16 * LDSTR + kc);
    bf16x8 bn0, bn1, bn2, bn3;
    if (kk < 15) {
      int kn = kc + 32;
      bn0 = *(const bf16x8*)(w4p + 0 * 16 * FD + kn);
      bn1 = *(const bf16x8*)(w4p + 1 * 16 * FD + kn);
      bn2 = *(const bf16x8*)(w4p + 2 * 16 * FD + kn);
      bn3 = *(const bf16x8*)(w4p + 3 * 16 * FD + kn);
    }
    acc[0][0] = __builtin_amdgcn_mfma_f32_16x16x32_bf16(af0, bc0, acc[0][0], 0, 0, 0);
    acc[1][0] = __builtin_amdgcn_mfma_f32_16x16x32_bf16(af1, bc0, acc[1][0], 0, 0, 0);
    acc[0][1] = __builtin_amdgcn_mfma_f32_16x16x32_bf16(af0, bc1, acc[0][1], 0, 0, 0);
    acc[1][1] = __builtin_amdgcn_mfma_f32_16x16x32_bf16(af1, bc1, acc[1][1], 0, 0, 0);
    acc[0][2] = __builtin_amdgcn_mfma_f32_16x16x32_bf16(af0, bc2, acc[0][2], 0, 0, 0);
    acc[1][2] = __builtin_amdgcn_mfma_f32_16x16x32_bf16(af1, bc2, acc[1][2], 0, 0, 0);
    acc[0][3] = __builtin_amdgcn_mfma_f32_16x16x32_bf16(af0, bc3, acc[0][3], 0, 0, 0);
    acc[1][3] = __builtin_amdgcn_mfma_f32_16x16x32_bf16(af1, bc3, acc[1][3], 0, 0, 0);
    bc0 = bn0; bc1 = bn1; bc2 = bn2; bc3 = bn3;
  }
  __syncthreads();  // done reading tileL

  // bounce acc -> LDS bf16 [32][268], then coalesced bf16 writeout of used rows
  ushort* ldsB = (ushort*)tileL;
  #pragma unroll
  for (int mi = 0; mi < 2; ++mi)
    #pragma unroll
    for (int ni = 0; ni < 4; ++ni)
      #pragma unroll
      for (int rr = 0; rr < 4; ++rr)
        ldsB[(16 * mi + 4 * q + rr) * 268 + 64 * w + 16 * ni + m] = f2bf(acc[mi][ni][rr]);
  __syncthreads();
  int hr = t >> 7, p = (t & 127) * 2;
  #pragma unroll
  for (int r = 0; r < 32; r += 2) {
    int rr = r + hr;
    if (cnOk[rr])
      *(uint*)&A[(size_t)(rowBase + rr) * F2 + p] = *(const uint*)&ldsB[rr * 268 + p];
  }
}

// ---------------- BN4 stats of h = A1[s]+A2[o]+A3[p]; also materialize h (bf16) ----------------
__global__ __launch_bounds__(256) void k_hstats(
    const int* __restrict__ subj, const int* __restrict__ obj,
    const int* __restrict__ predi,
    const ushort* __restrict__ A1, const ushort* __restrict__ A2,
    const ushort* __restrict__ A3, ushort* __restrict__ h,
    float* __restrict__ s4)
{
  __shared__ float colS[256], colQ[256];
  int t = threadIdx.x;
  colS[t] = 0.f; colQ[t] = 0.f;
  __syncthreads();
  int c = t & 31;       // lane c -> cols [8c,8c+8); 32 lanes cover one 512B bf16 row
  int pair = t >> 5;    // 8 half-waves, one sample each per iter
  float ls[8], lq[8];
  #pragma unroll
  for (int j = 0; j < 8; ++j) { ls[j] = 0.f; lq[j] = 0.f; }
  int base = blockIdx.x * 64;
  #pragma unroll 4
  for (int i = 0; i < 8; ++i) {
    int b = base + i * 8 + pair;
    bf16x8 v1 = *(const bf16x8*)(A1 + (size_t)subj[b]  * F2 + c * 8);
    bf16x8 v2 = *(const bf16x8*)(A2 + (size_t)obj[b]   * F2 + c * 8);
    bf16x8 v3 = *(const bf16x8*)(A3 + (size_t)predi[b] * F2 + c * 8);
    union { ushort o[8]; uint4 v; } u;
    #pragma unroll
    for (int j = 0; j < 8; ++j) {
      float hv = (float)v1[j] + (float)v2[j] + (float)v3[j];
      ls[j] += hv; lq[j] = fmaf(hv, hv, lq[j]);
      u.o[j] = f2bf(hv);
    }
    *(uint4*)&h[(size_t)b * F2 + c * 8] = u.v;
  }
  #pragma unroll
  for (int j = 0; j < 8; ++j) {
    atomicAdd(&colS[c * 8 + j], ls[j]);
    atomicAdd(&colQ[c * 8 + j], lq[j]);
  }
  __syncthreads();
  int slot = blockIdx.x & 63;
  atomicAdd(&s4[slot * 512 + t],       colS[t]);
  atomicAdd(&s4[slot * 512 + 256 + t], colQ[t]);
}

__global__ void k_fin4(const float* __restrict__ s4, const float* __restrict__ g4,
                       const float* __restrict__ be4, float* __restrict__ scsh4)
{
  int j = threadIdx.x;  // 256
  float S = 0.f, SS = 0.f;
  for (int sl = 0; sl < 64; ++sl) { S += s4[sl * 512 + j]; SS += s4[sl * 512 + 256 + j]; }
  const float invB = 1.f / (float)BATCHN;
  float mean = S * invB;
  float var  = SS * invB - mean * mean;
  if (!(var >= 0.f && var < 1e30f)) var = 1.f;
  if (!(mean > -1e30f && mean < 1e30f)) mean = 0.f;
  float r = rsqrtf(var + 1e-5f);
  float sc = g4[j] * r;
  scsh4[j]       = sc;
  scsh4[256 + j] = be4[j] - mean * sc;
}

// ---------------- final: stream h (bf16), BN4+relu+dot(W5)+b5 -> logits ----------------
__global__ __launch_bounds__(256) void k_final(
    const ushort* __restrict__ h, const float* __restrict__ scsh4,
    const float* __restrict__ W5, const float* __restrict__ b5,
    float* __restrict__ out)
{
  int t = threadIdx.x;
  int c = t & 31, pair = t >> 5;
  float sc4v[8], sh4v[8], w5v[8];
  #pragma unroll
  for (int j = 0; j < 8; ++j) {
    int col = c * 8 + j;
    sc4v[j] = scsh4[col];
    sh4v[j] = scsh4[256 + col];
    w5v[j]  = W5[col];
  }
  float bb = b5[0];
  int base = blockIdx.x * 64;
  #pragma unroll 4
  for (int i = 0; i < 8; ++i) {
    int b = base + i * 8 + pair;
    bf16x8 hv = *(const bf16x8*)(h + (size_t)b * F2 + c * 8);
    float acc = 0.f;
    #pragma unroll
    for (int j = 0; j < 8; ++j)
      acc += fmaxf(fmaf(sc4v[j], (float)hv[j], sh4v[j]), 0.f) * w5v[j];
    #pragma unroll
    for (int off = 1; off < 32; off <<= 1)
      acc += __shfl_xor(acc, off, 64);
    if (c == 0) out[b] = acc + bb;
  }
}

extern "C" void kernel_launch(void* const* d_in, const int* in_sizes, int n_in,
                              void* d_out, int out_size, void* d_ws, size_t ws_size,
                              hipStream_t stream)
{
  const int* subj  = (const int*)d_in[0];
  const int* obj   = (const int*)d_in[1];
  const int* predi = (const int*)d_in[2];
  const float* W1  = (const float*)d_in[3];
  // b1/b2/b3/b4 cancel inside their BatchNorms — never read
  const float* g1  = (const float*)d_in[5];
  const float* be1 = (const float*)d_in[6];
  const float* W2  = (const float*)d_in[7];
  const float* g2  = (const float*)d_in[9];
  const float* be2 = (const float*)d_in[10];
  const float* W3  = (const float*)d_in[11];
  const float* g3  = (const float*)d_in[13];
  const float* be3 = (const float*)d_in[14];
  const float* W4  = (const float*)d_in[15];
  const float* g4  = (const float*)d_in[17];
  const float* be4 = (const float*)d_in[18];
  const float* W5  = (const float*)d_in[19];
  const float* b5  = (const float*)d_in[20];

  float* wsf   = (float*)d_ws;
  int*   cnt   = (int*)d_ws;
  ushort* w4bf = (ushort*)(wsf + WS_W4BF);
  ushort* wbf1 = (ushort*)(wsf + WS_WBF1);
  ushort* wbf2 = (ushort*)(wsf + WS_WBF2);
  ushort* wbf3 = (ushort*)(wsf + WS_WBF3);
  ushort* A1   = (ushort*)(wsf + WS_A1);
  ushort* A2   = (ushort*)(wsf + WS_A2);
  ushort* A3   = (ushort*)(wsf + WS_A3);
  ushort* hbuf = (ushort*)(wsf + WS_H);
  float* out   = (float*)d_out;

  hipMemsetAsync(d_ws, 0, WS_SCSH123 * 4, stream);  // zero cnt + stats123 + s4
  k_hist<<<BATCHN / 256, 256, 0, stream>>>(subj, obj, predi, cnt);
  k_convW4<<<128, 256, 0, stream>>>(W4, w4bf);

  // stats (read-only scans)
  k_scan<<<(NOBJ + RPB - 1) / RPB, 256, 0, stream>>>(W1, cnt, wsf + WS_STATS123, NOBJ);
  k_scan<<<(NOBJ + RPB - 1) / RPB, 256, 0, stream>>>(W2, cnt + NOBJ, wsf + WS_STATS123 + 1024, NOBJ);
  k_scan<<<(NPRED + RPB - 1) / RPB, 256, 0, stream>>>(W3, cnt + 2 * NOBJ, wsf + WS_STATS123 + 2048, NPRED);
  k_fin123<<<3, 512, 0, stream>>>(wsf + WS_STATS123, g1, be1, g2, be2, g3, be3, wsf + WS_SCSH123);

  // W fp32 -> relu(bn(W)) bf16 (streaming)
  k_bnrelu<<<(NOBJ + RPB - 1) / RPB, 256, 0, stream>>>(W1, cnt, wsf + WS_SCSH123, wbf1, NOBJ);
  k_bnrelu<<<(NOBJ + RPB - 1) / RPB, 256, 0, stream>>>(W2, cnt + NOBJ, wsf + WS_SCSH123 + 1024, wbf2, NOBJ);
  k_bnrelu<<<(NPRED + RPB - 1) / RPB, 256, 0, stream>>>(W3, cnt + 2 * NOBJ, wsf + WS_SCSH123 + 2048, wbf3, NPRED);

  // pure GEMMs (gload_lds staging)
  k_gemmA<<<NOBJ / 32, 256, 0, stream>>>(wbf1, w4bf, cnt, A1, NOBJ);
  k_gemmA<<<NOBJ / 32, 256, 0, stream>>>(wbf2, w4bf, cnt + NOBJ, A2, NOBJ);
  k_gemmA<<<(NPRED + 31) / 32, 256, 0, stream>>>(wbf3, w4bf, cnt + 2 * NOBJ, A3, NPRED);

  // h = A1[s]+A2[o]+A3[p] (wbf1 dead -> h overlays it)
  k_hstats<<<BATCHN / 64, 256, 0, stream>>>(subj, obj, predi, A1, A2, A3, hbuf, wsf + WS_S4);
  k_fin4<<<1, 256, 0, stream>>>(wsf + WS_S4, g4, be4, wsf + WS_SCSH4);
  k_final<<<BATCHN / 64, 256, 0, stream>>>(hbuf, wsf + WS_SCSH4, W5, b5, out);
}

// Round 9
// 881.319 us; speedup vs baseline: 1.1116x; 1.1116x over previous
//
#include <hip/hip_runtime.h>

#define BATCHN 131072
#define FD 512
#define F2 256
#define NOBJ 100000
#define NPRED 2000
#define RPB 128     // rows per scanconv/bnrelu block
#define GR 128      // gemm rows per block
#define GK 32       // gemm k-step

typedef __bf16 bf16x8 __attribute__((ext_vector_type(8)));
typedef float f32x4 __attribute__((ext_vector_type(4)));

__device__ __forceinline__ ushort f2bf(float f) {
  union { float f; uint u; } c; c.f = f;
  uint u = c.u;
  u += 0x7FFFu + ((u >> 16) & 1u);   // RNE
  return (ushort)(u >> 16);
}

__device__ __forceinline__ void gload16(const void* g, void* l) {
  __builtin_amdgcn_global_load_lds(
      (const __attribute__((address_space(1))) void*)g,
      (__attribute__((address_space(3))) void*)l, 16, 0, 0);
}

// ---------------- ws layout (float units) ----------------
// cnt (int): subj[100000], obj[100000], predi[2000] at 0 / 100000 / 200000
#define WS_STATS123 202752   // 3*1024
#define WS_S4       205824   // 64 slots * [sum256, sumsq256]
#define WS_SCSH123  238592   // 3*1024
#define WS_SCSH4    241664   // 512
#define WS_W4BF     242176   // ushort[256*512] = 65536 floats
#define WS_WBF1     307712   // bf16[100000*512] = 25.6M floats
#define WS_WBF2     25907712
#define WS_WBF3     51507712 // bf16[2000*512]
#define WS_A1       52019712 // bf16[100000*256] = 12.8M floats
#define WS_A2       64819712
#define WS_A3       77619712 // bf16[2000*256]
// end: 77,875,712 floats = 311.5 MB (ws = 800 MB confirmed by fill counter)
#define WS_H        WS_WBF1  // h overlays WBF1 (dead after gemmA1)

// ---------------- histogram ----------------
__global__ __launch_bounds__(256) void k_hist(
    const int* __restrict__ subj, const int* __restrict__ obj,
    const int* __restrict__ predi, int* __restrict__ cnt)
{
  int b = blockIdx.x * 256 + threadIdx.x;
  atomicAdd(&cnt[subj[b]], 1);
  atomicAdd(&cnt[NOBJ + obj[b]], 1);
  atomicAdd(&cnt[2 * NOBJ + predi[b]], 1);
}

// ---------------- fused: weighted BN stats + raw bf16 copy (r6-proven) ----------------
__global__ __launch_bounds__(256) void k_scanconv(
    const float* __restrict__ W, const int* __restrict__ cn,
    float* __restrict__ statsE, ushort* __restrict__ wbf, int N)
{
  __shared__ float redS[512], redQ[512];
  int t = threadIdx.x;
  redS[t] = 0.f; redS[t + 256] = 0.f; redQ[t] = 0.f; redQ[t + 256] = 0.f;
  __syncthreads();
  int c = t & 63, rg = t >> 6;
  int base = blockIdx.x * RPB;
  int end = min(N, base + RPB);
  float s[8], q[8];
  #pragma unroll
  for (int j = 0; j < 8; ++j) { s[j] = 0.f; q[j] = 0.f; }

  #pragma unroll 4
  for (int r = base + rg; r < end; r += 4) {
    const float* row = W + (size_t)r * FD + c * 8;
    float4 va = *(const float4*)(row);
    float4 vb = *(const float4*)(row + 4);
    float wv = (float)cn[r];
    float x[8] = {va.x, va.y, va.z, va.w, vb.x, vb.y, vb.z, vb.w};
    union { ushort o[8]; uint4 v; } u;
    #pragma unroll
    for (int j = 0; j < 8; ++j) {
      float wx = wv * x[j];
      s[j] += wx; q[j] = fmaf(wx, x[j], q[j]);
      u.o[j] = f2bf(x[j]);
    }
    if (wv > 0.f) *(uint4*)&wbf[(size_t)r * FD + c * 8] = u.v;
  }

  #pragma unroll
  for (int j = 0; j < 8; ++j) {
    atomicAdd(&redS[c * 8 + j], s[j]);
    atomicAdd(&redQ[c * 8 + j], q[j]);
  }
  __syncthreads();
  atomicAdd(&statsE[t],        redS[t]);
  atomicAdd(&statsE[t + 256],  redS[t + 256]);
  atomicAdd(&statsE[512 + t],  redQ[t]);
  atomicAdd(&statsE[768 + t],  redQ[t + 256]);
}

__global__ void k_fin123(const float* __restrict__ stats,
                         const float* __restrict__ g1, const float* __restrict__ be1,
                         const float* __restrict__ g2, const float* __restrict__ be2,
                         const float* __restrict__ g3, const float* __restrict__ be3,
                         float* __restrict__ scsh)
{
  int e = blockIdx.x, f = threadIdx.x;  // 3 x 512
  const float* g  = (e == 0) ? g1  : (e == 1 ? g2  : g3);
  const float* be = (e == 0) ? be1 : (e == 1 ? be2 : be3);
  float S = stats[e * 1024 + f], SS = stats[e * 1024 + 512 + f];
  const float invB = 1.f / (float)BATCHN;
  float mean = S * invB;
  float var  = SS * invB - mean * mean;
  if (!(var >= 0.f && var < 1e30f)) var = 1.f;
  if (!(mean > -1e30f && mean < 1e30f)) mean = 0.f;
  float r = rsqrtf(var + 1e-5f);
  float sc = g[f] * r;
  scsh[e * 1024 + f]       = sc;
  scsh[e * 1024 + 512 + f] = be[f] - mean * sc;
}

// ---------------- in-place BN+relu on bf16 wbf (used rows only) ----------------
__global__ __launch_bounds__(256) void k_bnrelu2(
    const int* __restrict__ cn, const float* __restrict__ scshE,
    ushort* __restrict__ wbf, int N)
{
  int t = threadIdx.x;
  int c = t & 63, rg = t >> 6;
  float sc[8], sh[8];
  #pragma unroll
  for (int j = 0; j < 8; ++j) {
    sc[j] = scshE[c * 8 + j];
    sh[j] = scshE[512 + c * 8 + j];
  }
  int base = blockIdx.x * RPB;
  int end = min(N, base + RPB);
  #pragma unroll 4
  for (int r = base + rg; r < end; r += 4) {
    if (cn[r] == 0) continue;     // wave-uniform skip
    ushort* p = wbf + (size_t)r * FD + c * 8;
    union { uint4 v; ushort o[8]; } in; in.v = *(const uint4*)p;
    union { ushort o[8]; uint4 v; } out;
    #pragma unroll
    for (int j = 0; j < 8; ++j) {
      union { uint uu; float f; } cv; cv.uu = (uint)in.o[j] << 16;
      float v = fmaxf(fmaf(sc[j], cv.f, sh[j]), 0.f);
      v = fminf(v, 60000.f);
      out.o[j] = f2bf(v);
    }
    *(uint4*)p = out.v;
  }
}

// ---------------- W4 fp32 -> bf16 ----------------
__global__ __launch_bounds__(256) void k_convW4(const float* __restrict__ W4,
                                                ushort* __restrict__ w4bf)
{
  int i = (blockIdx.x * 256 + threadIdx.x) * 4;
  float4 v = *(const float4*)(W4 + i);
  ushort4 o = {f2bf(v.x), f2bf(v.y), f2bf(v.z), f2bf(v.w)};
  *(ushort4*)(w4bf + i) = o;
}

// ---------------- GEMM: A_out[128x256] = wbf_tile[128x512] @ w4bf^T ----------------
// 512 thr (8 waves, 2x4), K-stepped BK=32, dbuf gload_lds staging of A[128x32] and
// B[256x32]. XOR swizzle (rule #21): linear LDS dest, source k16^=(row&3), read
// slot=row*4+(q^(m&3)). B L2 traffic amortized 4x vs the 32-row version (the 123us cause).
__global__ __launch_bounds__(512) void k_gemmA(
    const ushort* __restrict__ wbf, const ushort* __restrict__ w4bf,
    const int* __restrict__ cn, ushort* __restrict__ A, int N)
{
  __shared__ ushort lds[128 * 268];   // 68.6 KB; stage dbuf carved at [0, 24576) ushorts
  __shared__ int cnOk[128];
  int t = threadIdx.x;
  int lane = t & 63, m = lane & 15, q = lane >> 4;
  int wv = t >> 6, wr = wv >> 2, wc = wv & 3;
  int rowBase = blockIdx.x * GR;

  if (t < 128) { int gr = rowBase + t; cnOk[t] = (gr < N) && (cn[gr] != 0); }

  f32x4 acc[4][4];
  #pragma unroll
  for (int mi = 0; mi < 4; ++mi)
    #pragma unroll
    for (int ni = 0; ni < 4; ++ni)
      acc[mi][ni] = (f32x4){0.f, 0.f, 0.f, 0.f};

  // ---- stage step 0 ----
  {
    int kc = 0;
    // A: 512 slots, 1 gload
    { int s = t, row = s >> 2, cc = s & 3;
      int gr = rowBase + row; if (gr >= N) gr = N - 1;
      gload16(wbf + (size_t)gr * FD + kc + ((cc ^ (row & 3)) * 8),
              lds + (size_t)(s & ~63) * 8); }
    // B: 1024 slots, 2 gloads
    #pragma unroll
    for (int gg = 0; gg < 2; ++gg) {
      int s = gg * 512 + t, n = s >> 2, cc = s & 3;
      gload16(w4bf + (size_t)n * FD + kc + ((cc ^ (n & 3)) * 8),
              lds + 4096 + (size_t)(s & ~63) * 8);
    }
  }
  __syncthreads();

  for (int ks = 0; ks < 16; ++ks) {
    int cur = ks & 1;
    if (ks < 15) {                      // prefetch next chunk into other buffer
      int kc = (ks + 1) * GK;
      ushort* base = lds + (cur ^ 1) * 12288;
      { int s = t, row = s >> 2, cc = s & 3;
        int gr = rowBase + row; if (gr >= N) gr = N - 1;
        gload16(wbf + (size_t)gr * FD + kc + ((cc ^ (row & 3)) * 8),
                base + (size_t)(s & ~63) * 8); }
      #pragma unroll
      for (int gg = 0; gg < 2; ++gg) {
        int s = gg * 512 + t, n = s >> 2, cc = s & 3;
        gload16(w4bf + (size_t)n * FD + kc + ((cc ^ (n & 3)) * 8),
                base + 4096 + (size_t)(s & ~63) * 8);
      }
    }
    // compute on buf[cur]
    const ushort* abase = lds + cur * 12288;
    const ushort* bbase = abase + 4096;
    bf16x8 af[4], bf[4];
    #pragma unroll
    for (int mi = 0; mi < 4; ++mi) {
      int row = wr * 64 + mi * 16 + m;
      af[mi] = *(const bf16x8*)(abase + (row * 4 + (q ^ (m & 3))) * 8);
    }
    #pragma unroll
    for (int ni = 0; ni < 4; ++ni) {
      int n = wc * 64 + ni * 16 + m;
      bf[ni] = *(const bf16x8*)(bbase + (n * 4 + (q ^ (m & 3))) * 8);
    }
    #pragma unroll
    for (int mi = 0; mi < 4; ++mi)
      #pragma unroll
      for (int ni = 0; ni < 4; ++ni)
        acc[mi][ni] = __builtin_amdgcn_mfma_f32_16x16x32_bf16(af[mi], bf[ni], acc[mi][ni], 0, 0, 0);
    __syncthreads();   // drains prefetch vmcnt; buf[cur] free for ks+2
  }

  // ---- bounce acc -> lds bf16 [128][268] (q-rows hit distinct bank groups), writeout ----
  #pragma unroll
  for (int mi = 0; mi < 4; ++mi)
    #pragma unroll
    for (int ni = 0; ni < 4; ++ni)
      #pragma unroll
      for (int rr = 0; rr < 4; ++rr) {
        int row = wr * 64 + mi * 16 + q * 4 + rr;
        int col = wc * 64 + ni * 16 + m;
        lds[row * 268 + col] = f2bf(acc[mi][ni][rr]);
      }
  __syncthreads();
  int sr = t >> 7, p = (t & 127) * 2;   // 4 rows/pass; thread -> 2 bf16 -> 1 uint
  #pragma unroll
  for (int r0 = 0; r0 < 128; r0 += 4) {
    int rr = r0 + sr;
    if (cnOk[rr])
      *(uint*)&A[(size_t)(rowBase + rr) * F2 + p] = *(const uint*)&lds[rr * 268 + p];
  }
}

// ---------------- BN4 stats of h = A1[s]+A2[o]+A3[p]; materialize h (bf16) ----------------
__global__ __launch_bounds__(256) void k_hstats(
    const int* __restrict__ subj, const int* __restrict__ obj,
    const int* __restrict__ predi,
    const ushort* __restrict__ A1, const ushort* __restrict__ A2,
    const ushort* __restrict__ A3, ushort* __restrict__ h,
    float* __restrict__ s4)
{
  __shared__ float colS[256], colQ[256];
  int t = threadIdx.x;
  colS[t] = 0.f; colQ[t] = 0.f;
  __syncthreads();
  int c = t & 31, pair = t >> 5;
  float ls[8], lq[8];
  #pragma unroll
  for (int j = 0; j < 8; ++j) { ls[j] = 0.f; lq[j] = 0.f; }
  int base = blockIdx.x * 64;
  #pragma unroll 4
  for (int i = 0; i < 8; ++i) {
    int b = base + i * 8 + pair;
    bf16x8 v1 = *(const bf16x8*)(A1 + (size_t)subj[b]  * F2 + c * 8);
    bf16x8 v2 = *(const bf16x8*)(A2 + (size_t)obj[b]   * F2 + c * 8);
    bf16x8 v3 = *(const bf16x8*)(A3 + (size_t)predi[b] * F2 + c * 8);
    union { ushort o[8]; uint4 v; } u;
    #pragma unroll
    for (int j = 0; j < 8; ++j) {
      float hv = (float)v1[j] + (float)v2[j] + (float)v3[j];
      ls[j] += hv; lq[j] = fmaf(hv, hv, lq[j]);
      u.o[j] = f2bf(hv);
    }
    *(uint4*)&h[(size_t)b * F2 + c * 8] = u.v;
  }
  #pragma unroll
  for (int j = 0; j < 8; ++j) {
    atomicAdd(&colS[c * 8 + j], ls[j]);
    atomicAdd(&colQ[c * 8 + j], lq[j]);
  }
  __syncthreads();
  int slot = blockIdx.x & 63;
  atomicAdd(&s4[slot * 512 + t],       colS[t]);
  atomicAdd(&s4[slot * 512 + 256 + t], colQ[t]);
}

__global__ void k_fin4(const float* __restrict__ s4, const float* __restrict__ g4,
                       const float* __restrict__ be4, float* __restrict__ scsh4)
{
  int j = threadIdx.x;  // 256
  float S = 0.f, SS = 0.f;
  for (int sl = 0; sl < 64; ++sl) { S += s4[sl * 512 + j]; SS += s4[sl * 512 + 256 + j]; }
  const float invB = 1.f / (float)BATCHN;
  float mean = S * invB;
  float var  = SS * invB - mean * mean;
  if (!(var >= 0.f && var < 1e30f)) var = 1.f;
  if (!(mean > -1e30f && mean < 1e30f)) mean = 0.f;
  float r = rsqrtf(var + 1e-5f);
  float sc = g4[j] * r;
  scsh4[j]       = sc;
  scsh4[256 + j] = be4[j] - mean * sc;
}

// ---------------- final: stream h, BN4+relu+dot(W5)+b5 -> logits ----------------
__global__ __launch_bounds__(256) void k_final(
    const ushort* __restrict__ h, const float* __restrict__ scsh4,
    const float* __restrict__ W5, const float* __restrict__ b5,
    float* __restrict__ out)
{
  int t = threadIdx.x;
  int c = t & 31, pair = t >> 5;
  float sc4v[8], sh4v[8], w5v[8];
  #pragma unroll
  for (int j = 0; j < 8; ++j) {
    int col = c * 8 + j;
    sc4v[j] = scsh4[col];
    sh4v[j] = scsh4[256 + col];
    w5v[j]  = W5[col];
  }
  float bb = b5[0];
  int base = blockIdx.x * 64;
  #pragma unroll 4
  for (int i = 0; i < 8; ++i) {
    int b = base + i * 8 + pair;
    bf16x8 hv = *(const bf16x8*)(h + (size_t)b * F2 + c * 8);
    float acc = 0.f;
    #pragma unroll
    for (int j = 0; j < 8; ++j)
      acc += fmaxf(fmaf(sc4v[j], (float)hv[j], sh4v[j]), 0.f) * w5v[j];
    #pragma unroll
    for (int off = 1; off < 32; off <<= 1)
      acc += __shfl_xor(acc, off, 64);
    if (c == 0) out[b] = acc + bb;
  }
}

extern "C" void kernel_launch(void* const* d_in, const int* in_sizes, int n_in,
                              void* d_out, int out_size, void* d_ws, size_t ws_size,
                              hipStream_t stream)
{
  const int* subj  = (const int*)d_in[0];
  const int* obj   = (const int*)d_in[1];
  const int* predi = (const int*)d_in[2];
  const float* W1  = (const float*)d_in[3];
  // b1/b2/b3/b4 cancel inside their BatchNorms — never read
  const float* g1  = (const float*)d_in[5];
  const float* be1 = (const float*)d_in[6];
  const float* W2  = (const float*)d_in[7];
  const float* g2  = (const float*)d_in[9];
  const float* be2 = (const float*)d_in[10];
  const float* W3  = (const float*)d_in[11];
  const float* g3  = (const float*)d_in[13];
  const float* be3 = (const float*)d_in[14];
  const float* W4  = (const float*)d_in[15];
  const float* g4  = (const float*)d_in[17];
  const float* be4 = (const float*)d_in[18];
  const float* W5  = (const float*)d_in[19];
  const float* b5  = (const float*)d_in[20];

  float* wsf   = (float*)d_ws;
  int*   cnt   = (int*)d_ws;
  ushort* w4bf = (ushort*)(wsf + WS_W4BF);
  ushort* wbf1 = (ushort*)(wsf + WS_WBF1);
  ushort* wbf2 = (ushort*)(wsf + WS_WBF2);
  ushort* wbf3 = (ushort*)(wsf + WS_WBF3);
  ushort* A1   = (ushort*)(wsf + WS_A1);
  ushort* A2   = (ushort*)(wsf + WS_A2);
  ushort* A3   = (ushort*)(wsf + WS_A3);
  ushort* hbuf = (ushort*)(wsf + WS_H);
  float* out   = (float*)d_out;

  hipMemsetAsync(d_ws, 0, WS_SCSH123 * 4, stream);  // zero cnt + stats123 + s4
  k_hist<<<BATCHN / 256, 256, 0, stream>>>(subj, obj, predi, cnt);
  k_convW4<<<128, 256, 0, stream>>>(W4, w4bf);

  // pass 1: stats + raw bf16 copy (fused, one W read)
  k_scanconv<<<(NOBJ + RPB - 1) / RPB, 256, 0, stream>>>(W1, cnt, wsf + WS_STATS123, wbf1, NOBJ);
  k_scanconv<<<(NOBJ + RPB - 1) / RPB, 256, 0, stream>>>(W2, cnt + NOBJ, wsf + WS_STATS123 + 1024, wbf2, NOBJ);
  k_scanconv<<<(NPRED + RPB - 1) / RPB, 256, 0, stream>>>(W3, cnt + 2 * NOBJ, wsf + WS_STATS123 + 2048, wbf3, NPRED);
  k_fin123<<<3, 512, 0, stream>>>(wsf + WS_STATS123, g1, be1, g2, be2, g3, be3, wsf + WS_SCSH123);

  // pass 1.5: BN+relu in place on bf16 (light)
  k_bnrelu2<<<(NOBJ + RPB - 1) / RPB, 256, 0, stream>>>(cnt, wsf + WS_SCSH123, wbf1, NOBJ);
  k_bnrelu2<<<(NOBJ + RPB - 1) / RPB, 256, 0, stream>>>(cnt + NOBJ, wsf + WS_SCSH123 + 1024, wbf2, NOBJ);
  k_bnrelu2<<<(NPRED + RPB - 1) / RPB, 256, 0, stream>>>(cnt + 2 * NOBJ, wsf + WS_SCSH123 + 2048, wbf3, NPRED);

  // pass 2: 128x256 tiled GEMMs
  k_gemmA<<<(NOBJ + GR - 1) / GR, 512, 0, stream>>>(wbf1, w4bf, cnt, A1, NOBJ);
  k_gemmA<<<(NOBJ + GR - 1) / GR, 512, 0, stream>>>(wbf2, w4bf, cnt + NOBJ, A2, NOBJ);
  k_gemmA<<<(NPRED + GR - 1) / GR, 512, 0, stream>>>(wbf3, w4bf, cnt + 2 * NOBJ, A3, NPRED);

  // h = A1[s]+A2[o]+A3[p] (wbf1 dead -> h overlays it)
  k_hstats<<<BATCHN / 64, 256, 0, stream>>>(subj, obj, predi, A1, A2, A3, hbuf, wsf + WS_S4);
  k_fin4<<<1, 256, 0, stream>>>(wsf + WS_S4, g4, be4, wsf + WS_SCSH4);
  k_final<<<BATCHN / 64, 256, 0, stream>>>(hbuf, wsf + WS_SCSH4, W5, b5, out);
}